// Round 8
// baseline (248.624 us; speedup 1.0000x reference)
//
#include <hip/hip_runtime.h>
#include <hip/hip_bf16.h>

typedef unsigned short u16;
typedef __attribute__((ext_vector_type(8))) short bf16x8;
typedef __attribute__((ext_vector_type(4))) float f32x4;
typedef __attribute__((address_space(3))) unsigned lds_u32;
typedef const __attribute__((address_space(1))) unsigned glb_u32;

#define N 256
#define D 128
#define NH 4
#define KD 32
#define NN 65536
#define QK_SCALE 0.17677669529663687f
#define LOG2E 1.4426950408889634f
#define HUGE_MASK 32768.0f

__device__ __forceinline__ float b2f(u16 s) {
  union { float f; unsigned u; } x; x.u = ((unsigned)s) << 16; return x.f;
}
__device__ __forceinline__ u16 f2b(float f) {
  union { float f; unsigned u; } x; x.f = f;
  unsigned r = x.u + 0x7fff + ((x.u >> 16) & 1);
  return (u16)(r >> 16);
}
// raw v_exp_f32: computes 2^x (base-2 softmax; logits pre-scaled by log2e)
__device__ __forceinline__ float exp2v(float x) {
  float r; __asm__("v_exp_f32 %0, %1" : "=v"(r) : "v"(x)); return r;
}

// ---- Kernel 0: convert 5 weight mats fp32 -> bf16, PLAIN row-major layout.
// Weights are L2-resident broadcast data; consumers read B-fragments directly
// from global (no LDS staging), so no swizzle is needed anymore.
__global__ __launch_bounds__(256) void prep_w_kernel(
    const float* __restrict__ wq, const float* __restrict__ wk,
    const float* __restrict__ wv, const float* __restrict__ wg,
    const float* __restrict__ wo, u16* __restrict__ wb)
{
  int idx = blockIdx.x * 256 + threadIdx.x;          // 0 .. 10239
  const float* srcs[5] = {wq, wk, wv, wg, wo};
  int mat = idx >> 11, rem = idx & 2047;
  int row = rem >> 4, g = rem & 15;
  const float* s = srcs[mat] + row * 128 + g * 8;
  float4 f0 = *(const float4*)(s);
  float4 f1 = *(const float4*)(s + 4);
  uint4 pk;
  pk.x = (unsigned)f2b(f0.x) | ((unsigned)f2b(f0.y) << 16);
  pk.y = (unsigned)f2b(f0.z) | ((unsigned)f2b(f0.w) << 16);
  pk.z = (unsigned)f2b(f1.x) | ((unsigned)f2b(f1.y) << 16);
  pk.w = (unsigned)f2b(f1.z) | ((unsigned)f2b(f1.w) << 16);
  *(uint4*)(wb + (size_t)mat * 16384 + row * 128 + g * 8) = pk;
}

// Linear global->LDS DMA: CPW 1-KB chunks per wave (64 lanes x 16 B each).
template <int CPW>
__device__ __forceinline__ void stage_lin(const u16* __restrict__ gsrc, u16* lds, int tid) {
  int lane = tid & 63, wave = tid >> 6;
#pragma unroll
  for (int p = 0; p < CPW; p++) {
    int c = wave * CPW + p;                // chunk id, 512 u16 each
    __builtin_amdgcn_global_load_lds((glb_u32*)(gsrc + c * 512 + lane * 8),
                                     (lds_u32*)(lds + c * 512), 16, 0, 0);
  }
}

// ---------------- Kernel 1: fused LN + nb + q,k,v,g projections --------------
// Grid 1024 x 256thr (4 waves, 64 rows/block, 16 rows/wave). ZERO LDS, zero
// barriers: weight B-fragments are read directly from the global bf16 image
// (L2-resident broadcast — round-7 lesson: LDS staging cost 2 blocks/CU +
// 4 barrier phases + 2.1M bank conflicts for data every CU shares).
// nb stored NATURAL [h][i][j], PRE-SCALED by log2e. q scaled by QK_SCALE*log2e.
// K and V are stored as per-(r,h) LDS FRAGMENT IMAGES for attn's linear DMA:
//   kf[(r*4+h)*8192 + ((t*4+qc)*16+lrj)*8 + s]
//   vf[(r*4+h)*8192 + (((ks*2+e)*4+qv)*16+l)*8 + jv]
__global__ __launch_bounds__(256) void projln_kernel(
    const float* __restrict__ pa, const float* __restrict__ lns, const float* __restrict__ lnb,
    const float* __restrict__ w2d, const u16* __restrict__ wb, const float* __restrict__ bg,
    u16* __restrict__ q, u16* __restrict__ kf, u16* __restrict__ vf, u16* __restrict__ g,
    float* __restrict__ nb)
{
  int tid = threadIdx.x;
  int wave = tid >> 6, lane = tid & 63;
  int lr = lane & 15, quad = lane >> 4;

  bf16x8 a[4];
  int row = blockIdx.x * 64 + wave * 16 + lr;
  {
    const float* rp = pa + (size_t)row * D;
    float xv[4][8];
    float s = 0.f, ss = 0.f;
#pragma unroll
    for (int ks = 0; ks < 4; ks++) {
      float4 a0 = *(const float4*)(rp + ks * 32 + quad * 8);
      float4 a1 = *(const float4*)(rp + ks * 32 + quad * 8 + 4);
      xv[ks][0] = a0.x; xv[ks][1] = a0.y; xv[ks][2] = a0.z; xv[ks][3] = a0.w;
      xv[ks][4] = a1.x; xv[ks][5] = a1.y; xv[ks][6] = a1.z; xv[ks][7] = a1.w;
#pragma unroll
      for (int j = 0; j < 8; j++) { s += xv[ks][j]; ss += xv[ks][j] * xv[ks][j]; }
    }
    s  += __shfl_xor(s, 16, 64);  ss += __shfl_xor(ss, 16, 64);
    s  += __shfl_xor(s, 32, 64);  ss += __shfl_xor(ss, 32, 64);
    float mu = s * (1.0f / D);
    float var = ss * (1.0f / D) - mu * mu;
    float rs = rsqrtf(var + 1e-5f);
#pragma unroll
    for (int ks = 0; ks < 4; ks++) {
      float4 s0 = *(const float4*)(lns + ks * 32 + quad * 8);
      float4 s1 = *(const float4*)(lns + ks * 32 + quad * 8 + 4);
      float4 b0 = *(const float4*)(lnb + ks * 32 + quad * 8);
      float4 b1 = *(const float4*)(lnb + ks * 32 + quad * 8 + 4);
      float sc[8] = {s0.x,s0.y,s0.z,s0.w,s1.x,s1.y,s1.z,s1.w};
      float bi[8] = {b0.x,b0.y,b0.z,b0.w,b1.x,b1.y,b1.z,b1.w};
#pragma unroll
      for (int j = 0; j < 8; j++) xv[ks][j] = (xv[ks][j] - mu) * rs * sc[j] + bi[j];
    }
#pragma unroll
    for (int h = 0; h < NH; h++) {
      float p = 0.f;
#pragma unroll
      for (int ks = 0; ks < 4; ks++) {
        float4 w0 = *(const float4*)(w2d + h * D + ks * 32 + quad * 8);
        float4 w1 = *(const float4*)(w2d + h * D + ks * 32 + quad * 8 + 4);
        p += xv[ks][0]*w0.x + xv[ks][1]*w0.y + xv[ks][2]*w0.z + xv[ks][3]*w0.w
           + xv[ks][4]*w1.x + xv[ks][5]*w1.y + xv[ks][6]*w1.z + xv[ks][7]*w1.w;
      }
      p += __shfl_xor(p, 16, 64);
      p += __shfl_xor(p, 32, 64);
      if (quad == 0)
        nb[(size_t)h * NN + row] = p * LOG2E;   // base-2 domain, coalesced
    }
#pragma unroll
    for (int ks = 0; ks < 4; ks++)
#pragma unroll
      for (int j = 0; j < 8; j++) a[ks][j] = (short)f2b(xv[ks][j]);
  }

#pragma unroll 1
  for (int mat = 0; mat < 4; mat++) {
    const u16* W = wb + (size_t)mat * 16384;   // plain [nrow*128 + col]
    f32x4 acc[2][4];
#pragma unroll
    for (int tg = 0; tg < 2; tg++)
#pragma unroll
      for (int e = 0; e < 4; e++) acc[tg][e] = (f32x4){0.f, 0.f, 0.f, 0.f};
#pragma unroll
    for (int ks = 0; ks < 4; ks++) {
#pragma unroll
      for (int tg = 0; tg < 2; tg++) {
#pragma unroll
        for (int e = 0; e < 4; e++) {
          int nrow = tg * 64 + 4 * lr + e;
          bf16x8 b = *(const bf16x8*)(W + nrow * 128 + ks * 32 + quad * 8);
          acc[tg][e] = __builtin_amdgcn_mfma_f32_16x16x32_bf16(a[ks], b, acc[tg][e], 0, 0, 0);
        }
      }
    }
    int row0 = blockIdx.x * 64 + wave * 16 + quad * 4;
#pragma unroll
    for (int tg = 0; tg < 2; tg++) {
      int c0 = tg * 64 + 4 * lr;
      float bg0 = 0.f, bg1 = 0.f, bg2 = 0.f, bg3 = 0.f;
      if (mat == 3) { bg0 = bg[c0]; bg1 = bg[c0+1]; bg2 = bg[c0+2]; bg3 = bg[c0+3]; }
#pragma unroll
      for (int reg = 0; reg < 4; reg++) {
        float v0 = acc[tg][0][reg], v1 = acc[tg][1][reg];
        float v2 = acc[tg][2][reg], v3 = acc[tg][3][reg];
        if (mat == 0) {
          v0 *= QK_SCALE * LOG2E; v1 *= QK_SCALE * LOG2E;
          v2 *= QK_SCALE * LOG2E; v3 *= QK_SCALE * LOG2E;
        }
        if (mat == 3) {
          v0 = 1.0f / (1.0f + __expf(-(v0 + bg0)));
          v1 = 1.0f / (1.0f + __expf(-(v1 + bg1)));
          v2 = 1.0f / (1.0f + __expf(-(v2 + bg2)));
          v3 = 1.0f / (1.0f + __expf(-(v3 + bg3)));
        }
        int R = row0 + reg;                     // global row (r*256 + j)
        if (mat == 1) {
          // K fragment image store (8 B, 4 cols)
          int rr = R >> 8, j = R & 255;
          int t = j >> 4, lrj = j & 15;
          int h2 = c0 >> 5, cc = c0 & 31, qc = cc >> 3, s2 = cc & 7;
          uint2 pk;
          pk.x = (unsigned)f2b(v0) | ((unsigned)f2b(v1) << 16);
          pk.y = (unsigned)f2b(v2) | ((unsigned)f2b(v3) << 16);
          *(uint2*)(kf + (size_t)(rr * NH + h2) * 8192 +
                    ((t * 4 + qc) * 16 + lrj) * 8 + s2) = pk;
        } else if (mat == 2) {
          // V fragment image store (pi-permuted; 4 scalar u16 stores)
          int rr = R >> 8, j = R & 255;
          int ks2 = j >> 5, jrel = j & 31;
          int qv = (jrel & 15) >> 2;
          int jv = (jrel & 3) | ((jrel >> 4) << 2);
          int h2 = c0 >> 5, cc = c0 & 31;
          size_t base = (size_t)(rr * NH + h2) * 8192;
          u16 vs[4] = {f2b(v0), f2b(v1), f2b(v2), f2b(v3)};
#pragma unroll
          for (int i2 = 0; i2 < 4; i2++) {
            int c = cc + i2, e = c & 1, l = c >> 1;
            vf[base + (((ks2 * 2 + e) * 4 + qv) * 16 + l) * 8 + jv] = vs[i2];
          }
        } else {
          u16* O = (mat == 0) ? q : g;
          uint2 pk;
          pk.x = (unsigned)f2b(v0) | ((unsigned)f2b(v1) << 16);
          pk.y = (unsigned)f2b(v2) | ((unsigned)f2b(v3) << 16);
          *(uint2*)(O + (size_t)R * D + c0) = pk;
        }
      }
    }
  }
}

// ---------------- Kernel 2: attention per (r, h) — DMA-staged K/V ------------
// 256 thr (4 waves, 4 passes — round-4's best-measured shape) + linear DMA
// fragment-image staging (no scatter, no conflicts). LDS 33.8 KB -> 4
// blocks/CU x 4 waves = 16 waves/CU; VGPR ~52.
// Swapped QK^T, nb+bias in MFMA C-operand, base-2 online 2-chunk softmax,
// v_cvt_pk_bf16_f32 P-packing, per-output-row rescale via shuffles.
__global__ __launch_bounds__(256) void attn_kernel(
    const u16* __restrict__ q, const u16* __restrict__ kf, const u16* __restrict__ vf,
    const u16* __restrict__ g, const float* __restrict__ nb, const float* __restrict__ mask,
    u16* __restrict__ og)
{
  __shared__ __align__(16) u16 Kf[8192];
  __shared__ __align__(16) u16 Vf[8192];
  __shared__ float bias_lds[256];
  int h = blockIdx.x & 3, r = blockIdx.x >> 2;
  int tid = threadIdx.x;
  stage_lin<4>(kf + (size_t)(r * NH + h) * 8192, Kf, tid);
  stage_lin<4>(vf + (size_t)(r * NH + h) * 8192, Vf, tid);
  bias_lds[tid] = (HUGE_MASK * LOG2E) * (mask[r * N + tid] - 1.0f);
  __syncthreads();   // vmcnt drained by barrier semantics

  int wave = tid >> 6, lane = tid & 63;
  int lr = lane & 15, quad = lane >> 4;
  const float* nbh = nb + (size_t)h * NN;

  for (int pp = 0; pp < 4; pp++) {
    int i0 = pp * 64 + wave * 16;
    int irow = i0 + lr;
    bf16x8 af = *(const bf16x8*)(q + ((size_t)r * N + irow) * D + h * KD + quad * 8);
    const float* nbrow = nbh + (size_t)irow * N;
    float m = 0.f, ls = 0.f;
    f32x4 oa = (f32x4){0.f,0.f,0.f,0.f}, ob = (f32x4){0.f,0.f,0.f,0.f};
#pragma unroll 1
    for (int c = 0; c < 2; c++) {
      f32x4 S[8];
#pragma unroll
      for (int tt = 0; tt < 8; tt++) {
        int t = c * 8 + tt;
        int jb = t * 16 + quad * 4;
        float4 nb4 = *(const float4*)(nbrow + jb);
        float4 b4  = *(const float4*)(&bias_lds[jb]);
        f32x4 ci;
        ci[0] = nb4.x + b4.x; ci[1] = nb4.y + b4.y;
        ci[2] = nb4.z + b4.z; ci[3] = nb4.w + b4.w;
        bf16x8 kfr = *(const bf16x8*)(&Kf[((t * 4 + quad) * 16 + lr) * 8]);
        S[tt] = __builtin_amdgcn_mfma_f32_16x16x32_bf16(kfr, af, ci, 0, 0, 0);
      }
      float m0 = -3e38f, m1 = -3e38f, m2 = -3e38f, m3 = -3e38f;
#pragma unroll
      for (int tt = 0; tt < 8; tt++) {
        m0 = fmaxf(m0, S[tt][0]); m1 = fmaxf(m1, S[tt][1]);
        m2 = fmaxf(m2, S[tt][2]); m3 = fmaxf(m3, S[tt][3]);
      }
      float ma = fmaxf(fmaxf(m0, m1), fmaxf(m2, m3));
      ma = fmaxf(ma, __shfl_xor(ma, 16, 64));
      ma = fmaxf(ma, __shfl_xor(ma, 32, 64));
      if (c == 0) {
        m = ma;                                  // first chunk: no rescale
      } else {
        float mnew = fmaxf(m, ma);
        float sc = exp2v(m - mnew);              // row-lr domain
        m = mnew;
        ls *= sc;
        // oa/ob[reg] is row i0+quad*4+reg -> fetch that row's sc
        float s0 = __shfl(sc, quad * 4 + 0, 64);
        float s1 = __shfl(sc, quad * 4 + 1, 64);
        float s2 = __shfl(sc, quad * 4 + 2, 64);
        float s3 = __shfl(sc, quad * 4 + 3, 64);
        oa[0] *= s0; oa[1] *= s1; oa[2] *= s2; oa[3] *= s3;
        ob[0] *= s0; ob[1] *= s1; ob[2] *= s2; ob[3] *= s3;
      }
#pragma unroll
      for (int kk = 0; kk < 4; kk++) {
        int ks = c * 4 + kk;
        float p0 = exp2v(S[2*kk][0] - m);
        float p1 = exp2v(S[2*kk][1] - m);
        float p2 = exp2v(S[2*kk][2] - m);
        float p3 = exp2v(S[2*kk][3] - m);
        float p4 = exp2v(S[2*kk+1][0] - m);
        float p5 = exp2v(S[2*kk+1][1] - m);
        float p6 = exp2v(S[2*kk+1][2] - m);
        float p7 = exp2v(S[2*kk+1][3] - m);
        ls += ((p0 + p1) + (p2 + p3)) + ((p4 + p5) + (p6 + p7));
        union { bf16x8 v; unsigned u[4]; } pa;
        __asm__("v_cvt_pk_bf16_f32 %0, %1, %2" : "=v"(pa.u[0]) : "v"(p0), "v"(p1));
        __asm__("v_cvt_pk_bf16_f32 %0, %1, %2" : "=v"(pa.u[1]) : "v"(p2), "v"(p3));
        __asm__("v_cvt_pk_bf16_f32 %0, %1, %2" : "=v"(pa.u[2]) : "v"(p4), "v"(p5));
        __asm__("v_cvt_pk_bf16_f32 %0, %1, %2" : "=v"(pa.u[3]) : "v"(p6), "v"(p7));
        bf16x8 vb0 = *(const bf16x8*)(&Vf[(((ks * 2 + 0) * 4 + quad) * 16 + lr) * 8]);
        oa = __builtin_amdgcn_mfma_f32_16x16x32_bf16(pa.v, vb0, oa, 0, 0, 0);
        bf16x8 vb1 = *(const bf16x8*)(&Vf[(((ks * 2 + 1) * 4 + quad) * 16 + lr) * 8]);
        ob = __builtin_amdgcn_mfma_f32_16x16x32_bf16(pa.v, vb1, ob, 0, 0, 0);
      }
    }
    float lsum = ls;
    lsum += __shfl_xor(lsum, 16, 64);
    lsum += __shfl_xor(lsum, 32, 64);
    float invd = __builtin_amdgcn_rcpf(lsum);   // every lane: 1/L[row lr]

#pragma unroll
    for (int reg = 0; reg < 4; reg++) {
      float inv = __shfl(invd, quad * 4 + reg, 64);  // L of row i0+4*quad+reg
      int i = i0 + quad * 4 + reg;
      size_t base = ((size_t)r * N + i) * D + h * KD + 2 * lr;
      unsigned gv = *(const unsigned*)(g + base);
      float r0 = oa[reg] * inv * b2f((u16)(gv & 0xffff));
      float r1 = ob[reg] * inv * b2f((u16)(gv >> 16));
      *(unsigned*)(og + base) = (unsigned)f2b(r0) | ((unsigned)f2b(r1) << 16);
    }
  }
}

// ---------------- Kernel 3: output projection — zero-LDS GEMM ----------------
// Grid 1024 x 256thr, 64 rows/block, 16 rows/wave. wo B-fragments read
// directly from the global bf16 image (L2-resident broadcast). No LDS,
// no barrier.
__global__ __launch_bounds__(256) void out_kernel(
    const u16* __restrict__ og, const u16* __restrict__ wob, const float* __restrict__ bo,
    const float* __restrict__ mask, float* __restrict__ out)
{
  int tid = threadIdx.x;
  int wave = tid >> 6, lane = tid & 63;
  int lr = lane & 15, quad = lane >> 4;
  bf16x8 a[4];
  int arow = blockIdx.x * 64 + wave * 16 + lr;
#pragma unroll
  for (int ks = 0; ks < 4; ks++)
    a[ks] = *(const bf16x8*)(og + (size_t)arow * D + ks * 32 + quad * 8);
  f32x4 acc[2][4];
#pragma unroll
  for (int tg = 0; tg < 2; tg++)
#pragma unroll
    for (int e = 0; e < 4; e++) acc[tg][e] = (f32x4){0.f, 0.f, 0.f, 0.f};
#pragma unroll
  for (int ks = 0; ks < 4; ks++) {
#pragma unroll
    for (int tg = 0; tg < 2; tg++) {
#pragma unroll
      for (int e = 0; e < 4; e++) {
        int nrow = tg * 64 + 4 * lr + e;
        bf16x8 b = *(const bf16x8*)(wob + nrow * 128 + ks * 32 + quad * 8);
        acc[tg][e] = __builtin_amdgcn_mfma_f32_16x16x32_bf16(a[ks], b, acc[tg][e], 0, 0, 0);
      }
    }
  }
  int row0 = blockIdx.x * 64 + wave * 16 + quad * 4;
#pragma unroll
  for (int tg = 0; tg < 2; tg++) {
    int c0 = tg * 64 + 4 * lr;
    float4 bo4 = *(const float4*)(bo + c0);
#pragma unroll
    for (int reg = 0; reg < 4; reg++) {
      int pos = row0 + reg;
      float mk = mask[pos];
      float4 o4;
      o4.x = (acc[tg][0][reg] + bo4.x) * mk;
      o4.y = (acc[tg][1][reg] + bo4.y) * mk;
      o4.z = (acc[tg][2][reg] + bo4.z) * mk;
      o4.w = (acc[tg][3][reg] + bo4.w) * mk;
      *(float4*)(out + (size_t)pos * D + c0) = o4;
    }
  }
}

extern "C" void kernel_launch(void* const* d_in, const int* in_sizes, int n_in,
                              void* d_out, int out_size, void* d_ws, size_t ws_size,
                              hipStream_t stream)
{
  const float* pa   = (const float*)d_in[0];
  const float* mask = (const float*)d_in[1];
  const float* lns  = (const float*)d_in[2];
  const float* lnb  = (const float*)d_in[3];
  const float* w2d  = (const float*)d_in[4];
  const float* wq   = (const float*)d_in[5];
  const float* wk   = (const float*)d_in[6];
  const float* wv   = (const float*)d_in[7];
  const float* wg   = (const float*)d_in[8];
  const float* bg   = (const float*)d_in[9];
  const float* wo   = (const float*)d_in[10];
  const float* bo   = (const float*)d_in[11];

  const size_t ARR = (size_t)NN * D;     // 8M elements
  u16* q  = (u16*)d_ws;
  u16* kf = q + ARR;                      // K fragment images [r][h][8192]
  u16* vf = kf + ARR;                     // V fragment images [r][h][8192]
  u16* g  = vf + ARR;
  u16* og = g + ARR;
  float* nb = (float*)(og + ARR);         // NH*NN floats, natural [h][i][j]
  u16* wb = (u16*)(nb + (size_t)NH * NN); // 5*16384 u16, plain bf16 image

  prep_w_kernel<<<40, 256, 0, stream>>>(wq, wk, wv, wg, wo, wb);
  projln_kernel<<<1024, 256, 0, stream>>>(pa, lns, lnb, w2d, wb, bg, q, kf, vf, g, nb);
  attn_kernel<<<N * NH, 256, 0, stream>>>(q, kf, vf, g, nb, mask, og);
  out_kernel<<<1024, 256, 0, stream>>>(og, wb + 4 * 16384, bo, mask, (float*)d_out);
}

// Round 11
// 183.154 us; speedup vs baseline: 1.3575x; 1.3575x over previous
//
#include <hip/hip_runtime.h>
#include <hip/hip_bf16.h>

typedef unsigned short u16;
typedef __attribute__((ext_vector_type(8))) short bf16x8;
typedef __attribute__((ext_vector_type(4))) float f32x4;
typedef __attribute__((address_space(3))) unsigned lds_u32;
typedef const __attribute__((address_space(1))) unsigned glb_u32;

#define N 256
#define D 128
#define NH 4
#define KD 32
#define NN 65536
#define QK_SCALE 0.17677669529663687f
#define LOG2E 1.4426950408889634f
#define HUGE_MASK 32768.0f

__device__ __forceinline__ float b2f(u16 s) {
  union { float f; unsigned u; } x; x.u = ((unsigned)s) << 16; return x.f;
}
__device__ __forceinline__ u16 f2b(float f) {
  union { float f; unsigned u; } x; x.f = f;
  unsigned r = x.u + 0x7fff + ((x.u >> 16) & 1);
  return (u16)(r >> 16);
}
// raw v_exp_f32: computes 2^x (base-2 softmax; logits pre-scaled by log2e)
__device__ __forceinline__ float exp2v(float x) {
  float r; __asm__("v_exp_f32 %0, %1" : "=v"(r) : "v"(x)); return r;
}

// ---- Kernel 0: convert 5 weight mats fp32 -> bf16 into the swizzled LDS
// image layout: wb[mat][row*128 + gp*8 + j] = bf16(W[row][g*8+j]),
// gp = (g + (row&15)) & 15. One 8-elem group per thread.
// One mat = 128x128 bf16 = 32 KB = 16384 u16.
__global__ __launch_bounds__(256) void prep_w_kernel(
    const float* __restrict__ wq, const float* __restrict__ wk,
    const float* __restrict__ wv, const float* __restrict__ wg,
    const float* __restrict__ wo, u16* __restrict__ wb)
{
  int idx = blockIdx.x * 256 + threadIdx.x;          // 0 .. 10239
  const float* srcs[5] = {wq, wk, wv, wg, wo};
  int mat = idx >> 11, rem = idx & 2047;
  int row = rem >> 4, g = rem & 15;
  int gp = (g + (row & 15)) & 15;
  const float* s = srcs[mat] + row * 128 + g * 8;
  float4 f0 = *(const float4*)(s);
  float4 f1 = *(const float4*)(s + 4);
  uint4 pk;
  pk.x = (unsigned)f2b(f0.x) | ((unsigned)f2b(f0.y) << 16);
  pk.y = (unsigned)f2b(f0.z) | ((unsigned)f2b(f0.w) << 16);
  pk.z = (unsigned)f2b(f1.x) | ((unsigned)f2b(f1.y) << 16);
  pk.w = (unsigned)f2b(f1.z) | ((unsigned)f2b(f1.w) << 16);
  *(uint4*)(wb + (size_t)mat * 16384 + row * 128 + gp * 8) = pk;
}

// Linear global->LDS DMA: CPW 1-KB chunks per wave (64 lanes x 16 B each).
template <int CPW>
__device__ __forceinline__ void stage_lin(const u16* __restrict__ gsrc, u16* lds, int tid) {
  int lane = tid & 63, wave = tid >> 6;
#pragma unroll
  for (int p = 0; p < CPW; p++) {
    int c = wave * CPW + p;                // chunk id, 512 u16 each
    __builtin_amdgcn_global_load_lds((glb_u32*)(gsrc + c * 512 + lane * 8),
                                     (lds_u32*)(lds + c * 512), 16, 0, 0);
  }
}

// ---------------- Kernel 1: fused LN + nb + q,k,v,g projections --------------
// Round-5's exact proven structure: grid 512 x 512thr (8 waves), 128 rows per
// block, one 16-row m-tile per wave; weights double-buffered (2 x 32 KB) via
// global_load_lds from pre-swizzled wb. nb stored NATURAL [h][i][j],
// PRE-SCALED by log2e (base-2 softmax). q scaled by QK_SCALE*log2e.
__global__ __launch_bounds__(512) void projln_kernel(
    const float* __restrict__ pa, const float* __restrict__ lns, const float* __restrict__ lnb,
    const float* __restrict__ w2d, const u16* __restrict__ wb, const float* __restrict__ bg,
    u16* __restrict__ q, u16* __restrict__ k, u16* __restrict__ v, u16* __restrict__ g,
    float* __restrict__ nb)
{
  __shared__ __align__(16) u16 Wl[2][16384];
  int tid = threadIdx.x;
  int wave = tid >> 6, lane = tid & 63;
  int lr = lane & 15, quad = lane >> 4;

  stage_lin<4>(wb, Wl[0], tid);   // mat 0 (32 KB) in flight while LN runs

  bf16x8 a[4];
  int row = blockIdx.x * 128 + wave * 16 + lr;
  {
    const float* rp = pa + (size_t)row * D;
    float xv[4][8];
    float s = 0.f, ss = 0.f;
#pragma unroll
    for (int ks = 0; ks < 4; ks++) {
      float4 a0 = *(const float4*)(rp + ks * 32 + quad * 8);
      float4 a1 = *(const float4*)(rp + ks * 32 + quad * 8 + 4);
      xv[ks][0] = a0.x; xv[ks][1] = a0.y; xv[ks][2] = a0.z; xv[ks][3] = a0.w;
      xv[ks][4] = a1.x; xv[ks][5] = a1.y; xv[ks][6] = a1.z; xv[ks][7] = a1.w;
#pragma unroll
      for (int j = 0; j < 8; j++) { s += xv[ks][j]; ss += xv[ks][j] * xv[ks][j]; }
    }
    s  += __shfl_xor(s, 16, 64);  ss += __shfl_xor(ss, 16, 64);
    s  += __shfl_xor(s, 32, 64);  ss += __shfl_xor(ss, 32, 64);
    float mu = s * (1.0f / D);
    float var = ss * (1.0f / D) - mu * mu;
    float rs = rsqrtf(var + 1e-5f);
#pragma unroll
    for (int ks = 0; ks < 4; ks++) {
      float4 s0 = *(const float4*)(lns + ks * 32 + quad * 8);
      float4 s1 = *(const float4*)(lns + ks * 32 + quad * 8 + 4);
      float4 b0 = *(const float4*)(lnb + ks * 32 + quad * 8);
      float4 b1 = *(const float4*)(lnb + ks * 32 + quad * 8 + 4);
      float sc[8] = {s0.x,s0.y,s0.z,s0.w,s1.x,s1.y,s1.z,s1.w};
      float bi[8] = {b0.x,b0.y,b0.z,b0.w,b1.x,b1.y,b1.z,b1.w};
#pragma unroll
      for (int j = 0; j < 8; j++) xv[ks][j] = (xv[ks][j] - mu) * rs * sc[j] + bi[j];
    }
#pragma unroll
    for (int h = 0; h < NH; h++) {
      float p = 0.f;
#pragma unroll
      for (int ks = 0; ks < 4; ks++) {
        float4 w0 = *(const float4*)(w2d + h * D + ks * 32 + quad * 8);
        float4 w1 = *(const float4*)(w2d + h * D + ks * 32 + quad * 8 + 4);
        p += xv[ks][0]*w0.x + xv[ks][1]*w0.y + xv[ks][2]*w0.z + xv[ks][3]*w0.w
           + xv[ks][4]*w1.x + xv[ks][5]*w1.y + xv[ks][6]*w1.z + xv[ks][7]*w1.w;
      }
      p += __shfl_xor(p, 16, 64);
      p += __shfl_xor(p, 32, 64);
      if (quad == 0)
        nb[(size_t)h * NN + row] = p * LOG2E;   // base-2 domain, coalesced
    }
#pragma unroll
    for (int ks = 0; ks < 4; ks++)
#pragma unroll
      for (int j = 0; j < 8; j++) a[ks][j] = (short)f2b(xv[ks][j]);
  }
  __syncthreads();   // drains mat-0 global_load_lds (vmcnt) + all waves ready

  u16* Os[4] = {q, k, v, g};
#pragma unroll
  for (int mat = 0; mat < 4; mat++) {
    if (mat < 3) stage_lin<4>(wb + (size_t)(mat + 1) * 16384, Wl[(mat + 1) & 1], tid);
    const u16* Wcur = Wl[mat & 1];
    f32x4 acc[2][4];
#pragma unroll
    for (int tg = 0; tg < 2; tg++)
#pragma unroll
      for (int e = 0; e < 4; e++) acc[tg][e] = (f32x4){0.f, 0.f, 0.f, 0.f};
#pragma unroll
    for (int ks = 0; ks < 4; ks++) {
#pragma unroll
      for (int tg = 0; tg < 2; tg++) {
#pragma unroll
        for (int e = 0; e < 4; e++) {
          int nrow = tg * 64 + 4 * lr + e;
          int gp = (ks * 4 + quad + (nrow & 15)) & 15;
          bf16x8 b = *(const bf16x8*)(&Wcur[nrow * 128 + gp * 8]);
          acc[tg][e] = __builtin_amdgcn_mfma_f32_16x16x32_bf16(a[ks], b, acc[tg][e], 0, 0, 0);
        }
      }
    }
    u16* O = Os[mat];
    int row0 = blockIdx.x * 128 + wave * 16 + quad * 4;
#pragma unroll
    for (int tg = 0; tg < 2; tg++) {
      int c0 = tg * 64 + 4 * lr;
      float bg0 = 0.f, bg1 = 0.f, bg2 = 0.f, bg3 = 0.f;
      if (mat == 3) { bg0 = bg[c0]; bg1 = bg[c0+1]; bg2 = bg[c0+2]; bg3 = bg[c0+3]; }
#pragma unroll
      for (int reg = 0; reg < 4; reg++) {
        float v0 = acc[tg][0][reg], v1 = acc[tg][1][reg];
        float v2 = acc[tg][2][reg], v3 = acc[tg][3][reg];
        if (mat == 0) {
          v0 *= QK_SCALE * LOG2E; v1 *= QK_SCALE * LOG2E;
          v2 *= QK_SCALE * LOG2E; v3 *= QK_SCALE * LOG2E;
        }
        if (mat == 3) {
          v0 = 1.0f / (1.0f + __expf(-(v0 + bg0)));
          v1 = 1.0f / (1.0f + __expf(-(v1 + bg1)));
          v2 = 1.0f / (1.0f + __expf(-(v2 + bg2)));
          v3 = 1.0f / (1.0f + __expf(-(v3 + bg3)));
        }
        uint2 pk;
        pk.x = (unsigned)f2b(v0) | ((unsigned)f2b(v1) << 16);
        pk.y = (unsigned)f2b(v2) | ((unsigned)f2b(v3) << 16);
        *(uint2*)(O + (size_t)(row0 + reg) * D + c0) = pk;
      }
    }
    __syncthreads();   // next buffer staged (vmcnt drained) + reads done
  }
}

// ---------------- Kernel 2: attention per (r, h) — round-4 exact -------------
// 256 thr, 4 waves, 4 passes; in-kernel K/V LDS staging (pi-permuted V
// scatter); natural nb[h][i][j] float4 C-operand reads. LDS 33.8 KB -> 4
// blocks/CU, grid 1024 = exactly 4/CU, VGPR ~52. Swapped QK^T, nb+bias in
// MFMA C-operand, base-2 online 2-chunk softmax, v_cvt_pk_bf16_f32 packing,
// per-output-row rescale via shuffles. Measured 51.5 us, absmax 1.95e-3.
__global__ __launch_bounds__(256) void attn_kernel(
    const u16* __restrict__ q, const u16* __restrict__ k, const u16* __restrict__ v,
    const u16* __restrict__ g, const float* __restrict__ nb, const float* __restrict__ mask,
    u16* __restrict__ og)
{
  __shared__ __align__(16) u16 Kf[8192];
  __shared__ __align__(16) u16 Vf[8192];
  __shared__ float bias_lds[256];
  int h = blockIdx.x & 3, r = blockIdx.x >> 2;
  int tid = threadIdx.x;
  {
    int j = tid;
    const u16* krow = k + ((size_t)r * N + j) * D + h * KD;
    int t = j >> 4, lrj = j & 15;
#pragma unroll
    for (int qc = 0; qc < 4; qc++)
      *(bf16x8*)(&Kf[((t * 4 + qc) * 16 + lrj) * 8]) = *(const bf16x8*)(krow + qc * 8);
    const u16* vrow = v + ((size_t)r * N + j) * D + h * KD;
    // inverse of pi: source j-rel -> (quad qv, elem jv) slot in the B-fragment
    int ksrc = j >> 5, jrel = j & 31;
    int qv, jv;
    if (jrel < 16) { qv = jrel >> 2; jv = jrel & 3; }
    else           { qv = (jrel & 15) >> 2; jv = 4 + (jrel & 3); }
#pragma unroll
    for (int c = 0; c < 32; c++)
      Vf[(((ksrc * 2 + (c & 1)) * 4 + qv) * 16 + (c >> 1)) * 8 + jv] = vrow[c];
    bias_lds[tid] = (HUGE_MASK * LOG2E) * (mask[r * N + tid] - 1.0f);
  }
  __syncthreads();
  int wave = tid >> 6, lane = tid & 63;
  int lr = lane & 15, quad = lane >> 4;
  const float* nbh = nb + (size_t)h * NN;

  for (int pass = 0; pass < 4; pass++) {
    int i0 = pass * 64 + wave * 16;
    int irow = i0 + lr;
    bf16x8 af = *(const bf16x8*)(q + ((size_t)r * N + irow) * D + h * KD + quad * 8);
    const float* nbrow = nbh + (size_t)irow * N;
    float m = 0.f, ls = 0.f;
    f32x4 oa = (f32x4){0.f,0.f,0.f,0.f}, ob = (f32x4){0.f,0.f,0.f,0.f};
#pragma unroll 1
    for (int c = 0; c < 2; c++) {
      f32x4 S[8];
#pragma unroll
      for (int tt = 0; tt < 8; tt++) {
        int t = c * 8 + tt;
        int jb = t * 16 + quad * 4;
        float4 nb4 = *(const float4*)(nbrow + jb);
        float4 b4  = *(const float4*)(&bias_lds[jb]);
        f32x4 ci;
        ci[0] = nb4.x + b4.x; ci[1] = nb4.y + b4.y;
        ci[2] = nb4.z + b4.z; ci[3] = nb4.w + b4.w;
        bf16x8 kfr = *(const bf16x8*)(&Kf[((t * 4 + quad) * 16 + lr) * 8]);
        S[tt] = __builtin_amdgcn_mfma_f32_16x16x32_bf16(kfr, af, ci, 0, 0, 0);
      }
      float m0 = -3e38f, m1 = -3e38f, m2 = -3e38f, m3 = -3e38f;
#pragma unroll
      for (int tt = 0; tt < 8; tt++) {
        m0 = fmaxf(m0, S[tt][0]); m1 = fmaxf(m1, S[tt][1]);
        m2 = fmaxf(m2, S[tt][2]); m3 = fmaxf(m3, S[tt][3]);
      }
      float ma = fmaxf(fmaxf(m0, m1), fmaxf(m2, m3));
      ma = fmaxf(ma, __shfl_xor(ma, 16, 64));
      ma = fmaxf(ma, __shfl_xor(ma, 32, 64));
      if (c == 0) {
        m = ma;                                  // first chunk: no rescale
      } else {
        float mnew = fmaxf(m, ma);
        float sc = exp2v(m - mnew);              // row-lr domain
        m = mnew;
        ls *= sc;
        // oa/ob[reg] is row i0+quad*4+reg -> fetch that row's sc
        float s0 = __shfl(sc, quad * 4 + 0, 64);
        float s1 = __shfl(sc, quad * 4 + 1, 64);
        float s2 = __shfl(sc, quad * 4 + 2, 64);
        float s3 = __shfl(sc, quad * 4 + 3, 64);
        oa[0] *= s0; oa[1] *= s1; oa[2] *= s2; oa[3] *= s3;
        ob[0] *= s0; ob[1] *= s1; ob[2] *= s2; ob[3] *= s3;
      }
#pragma unroll
      for (int kk = 0; kk < 4; kk++) {
        int ks = c * 4 + kk;
        float p0 = exp2v(S[2*kk][0] - m);
        float p1 = exp2v(S[2*kk][1] - m);
        float p2 = exp2v(S[2*kk][2] - m);
        float p3 = exp2v(S[2*kk][3] - m);
        float p4 = exp2v(S[2*kk+1][0] - m);
        float p5 = exp2v(S[2*kk+1][1] - m);
        float p6 = exp2v(S[2*kk+1][2] - m);
        float p7 = exp2v(S[2*kk+1][3] - m);
        ls += ((p0 + p1) + (p2 + p3)) + ((p4 + p5) + (p6 + p7));
        union { bf16x8 v; unsigned u[4]; } pa;
        __asm__("v_cvt_pk_bf16_f32 %0, %1, %2" : "=v"(pa.u[0]) : "v"(p0), "v"(p1));
        __asm__("v_cvt_pk_bf16_f32 %0, %1, %2" : "=v"(pa.u[1]) : "v"(p2), "v"(p3));
        __asm__("v_cvt_pk_bf16_f32 %0, %1, %2" : "=v"(pa.u[2]) : "v"(p4), "v"(p5));
        __asm__("v_cvt_pk_bf16_f32 %0, %1, %2" : "=v"(pa.u[3]) : "v"(p6), "v"(p7));
        bf16x8 vb0 = *(const bf16x8*)(&Vf[(((ks * 2 + 0) * 4 + quad) * 16 + lr) * 8]);
        oa = __builtin_amdgcn_mfma_f32_16x16x32_bf16(pa.v, vb0, oa, 0, 0, 0);
        bf16x8 vb1 = *(const bf16x8*)(&Vf[(((ks * 2 + 1) * 4 + quad) * 16 + lr) * 8]);
        ob = __builtin_amdgcn_mfma_f32_16x16x32_bf16(pa.v, vb1, ob, 0, 0, 0);
      }
    }
    float lsum = ls;
    lsum += __shfl_xor(lsum, 16, 64);
    lsum += __shfl_xor(lsum, 32, 64);
    float invd = __builtin_amdgcn_rcpf(lsum);   // every lane: 1/L[row lr]

#pragma unroll
    for (int reg = 0; reg < 4; reg++) {
      float inv = __shfl(invd, quad * 4 + reg, 64);  // L of row i0+4*quad+reg
      int i = i0 + quad * 4 + reg;
      size_t base = ((size_t)r * N + i) * D + h * KD + 2 * lr;
      unsigned gv = *(const unsigned*)(g + base);
      float r0 = oa[reg] * inv * b2f((u16)(gv & 0xffff));
      float r1 = ob[reg] * inv * b2f((u16)(gv >> 16));
      *(unsigned*)(og + base) = (unsigned)f2b(r0) | ((unsigned)f2b(r1) << 16);
    }
  }
}

// ---------------- Kernel 3: output projection (staged wo) --------------------
// Round-5 math exactly; shape change only: 256 thr, 64 rows/block, grid 1024
// -> 32 KB LDS allows 4 blocks/CU (was 2). og loads issued before the barrier.
__global__ __launch_bounds__(256) void out_kernel(
    const u16* __restrict__ og, const u16* __restrict__ wob, const float* __restrict__ bo,
    const float* __restrict__ mask, float* __restrict__ out)
{
  __shared__ __align__(16) u16 Wlds[16384];
  int tid = threadIdx.x;
  stage_lin<8>(wob, Wlds, tid);
  int wave = tid >> 6, lane = tid & 63;
  int lr = lane & 15, quad = lane >> 4;
  bf16x8 a[4];
  int arow = blockIdx.x * 64 + wave * 16 + lr;
#pragma unroll
  for (int ks = 0; ks < 4; ks++)
    a[ks] = *(const bf16x8*)(og + (size_t)arow * D + ks * 32 + quad * 8);
  __syncthreads();
  f32x4 acc[2][4];
#pragma unroll
  for (int tg = 0; tg < 2; tg++)
#pragma unroll
    for (int e = 0; e < 4; e++) acc[tg][e] = (f32x4){0.f, 0.f, 0.f, 0.f};
#pragma unroll
  for (int ks = 0; ks < 4; ks++) {
#pragma unroll
    for (int tg = 0; tg < 2; tg++) {
#pragma unroll
      for (int e = 0; e < 4; e++) {
        int nrow = tg * 64 + 4 * lr + e;
        int gp = (ks * 4 + quad + (nrow & 15)) & 15;
        bf16x8 b = *(const bf16x8*)(&Wlds[nrow * 128 + gp * 8]);
        acc[tg][e] = __builtin_amdgcn_mfma_f32_16x16x32_bf16(a[ks], b, acc[tg][e], 0, 0, 0);
      }
    }
  }
  int row0 = blockIdx.x * 64 + wave * 16 + quad * 4;
#pragma unroll
  for (int tg = 0; tg < 2; tg++) {
    int c0 = tg * 64 + 4 * lr;
    float4 bo4 = *(const float4*)(bo + c0);
#pragma unroll
    for (int reg = 0; reg < 4; reg++) {
      int pos = row0 + reg;
      float mk = mask[pos];
      float4 o4;
      o4.x = (acc[tg][0][reg] + bo4.x) * mk;
      o4.y = (acc[tg][1][reg] + bo4.y) * mk;
      o4.z = (acc[tg][2][reg] + bo4.z) * mk;
      o4.w = (acc[tg][3][reg] + bo4.w) * mk;
      *(float4*)(out + (size_t)pos * D + c0) = o4;
    }
  }
}

extern "C" void kernel_launch(void* const* d_in, const int* in_sizes, int n_in,
                              void* d_out, int out_size, void* d_ws, size_t ws_size,
                              hipStream_t stream)
{
  const float* pa   = (const float*)d_in[0];
  const float* mask = (const float*)d_in[1];
  const float* lns  = (const float*)d_in[2];
  const float* lnb  = (const float*)d_in[3];
  const float* w2d  = (const float*)d_in[4];
  const float* wq   = (const float*)d_in[5];
  const float* wk   = (const float*)d_in[6];
  const float* wv   = (const float*)d_in[7];
  const float* wg   = (const float*)d_in[8];
  const float* bg   = (const float*)d_in[9];
  const float* wo   = (const float*)d_in[10];
  const float* bo   = (const float*)d_in[11];

  const size_t ARR = (size_t)NN * D;     // 8M elements
  u16* q  = (u16*)d_ws;
  u16* k  = q + ARR;
  u16* v  = k + ARR;
  u16* g  = v + ARR;
  u16* og = g + ARR;
  float* nb = (float*)(og + ARR);         // NH*NN floats, natural [h][i][j]
  u16* wb = (u16*)(nb + (size_t)NH * NN); // 5*16384 u16, swizzled LDS image

  prep_w_kernel<<<40, 256, 0, stream>>>(wq, wk, wv, wg, wo, wb);
  projln_kernel<<<512, 512, 0, stream>>>(pa, lns, lnb, w2d, wb, bg, q, k, v, g, nb);
  attn_kernel<<<N * NH, 256, 0, stream>>>(q, k, v, g, nb, mask, og);
  out_kernel<<<1024, 256, 0, stream>>>(og, wb + 4 * 16384, bo, mask, (float*)d_out);
}